// Round 14
// baseline (605.349 us; speedup 1.0000x reference)
//
#include <hip/hip_runtime.h>
#include <hip/hip_bf16.h>
#include <math.h>

#define Bn 4096
#define Fn 1536
#define Hn 256
#define Cn 38
#define Kn 7
#define GBK 128
#define NCAND 12

typedef __attribute__((ext_vector_type(8))) short short8;
typedef __attribute__((ext_vector_type(4))) float f32x4;
typedef unsigned long long u64;
typedef unsigned int u32;
typedef unsigned short u16;

__device__ __forceinline__ void gld16(const void* g, void* l) {
  __builtin_amdgcn_global_load_lds((const __attribute__((address_space(1))) unsigned int*)g,
                                   (__attribute__((address_space(3))) unsigned int*)l, 16, 0, 0);
}

// ---------- BN param prep (f64): x = feat*A + C ----------
__global__ void k_prep(const float* __restrict__ g, const float* __restrict__ b,
                       const float* __restrict__ m, const float* __restrict__ v,
                       double* __restrict__ A64, double* __restrict__ C64) {
  int f = blockIdx.x * 256 + threadIdx.x;
  if (f < Fn) {
    double rs = 1.0 / sqrt((double)v[f] + 1e-5);
    double a = (double)g[f] * rs;
    A64[f] = a;
    C64[f] = (double)b[f] - (double)m[f] * a;
  }
}

// Ah/Al = bf16 hi/lo split of BN(features); fused sq[row]; fused deg init.
__global__ void k_bnsplit(const float* __restrict__ feat, const double* __restrict__ A64,
                          const double* __restrict__ C64,
                          u16* __restrict__ Ah, u16* __restrict__ Al, double* __restrict__ sq,
                          float* __restrict__ deg) {
  int row = blockIdx.x;
  int f0 = threadIdx.x * 8;
  const float* fr = feat + (size_t)row * Fn + f0;
  float4 a = *reinterpret_cast<const float4*>(fr);
  float4 b = *reinterpret_cast<const float4*>(fr + 4);
  float xs[8] = {a.x, a.y, a.z, a.w, b.x, b.y, b.z, b.w};
  short8 hv, lv;
  double ss = 0.0;
#pragma unroll
  for (int k = 0; k < 8; k++) {
    double xd = fma((double)xs[k], A64[f0 + k], C64[f0 + k]);
    ss = fma(xd, xd, ss);
    float x = (float)xd;
    __hip_bfloat16 h = __float2bfloat16(x);
    float hf = __bfloat162float(h);
    __hip_bfloat16 lo = __float2bfloat16(x - hf);
    hv[k] = (short)*reinterpret_cast<u16*>(&h);
    lv[k] = (short)*reinterpret_cast<u16*>(&lo);
  }
  *reinterpret_cast<short8*>(Ah + (size_t)row * Fn + f0) = hv;
  *reinterpret_cast<short8*>(Al + (size_t)row * Fn + f0) = lv;
#pragma unroll
  for (int o = 32; o; o >>= 1) ss += __shfl_down(ss, o);
  __shared__ double red[3];
  if ((threadIdx.x & 63) == 0) red[threadIdx.x >> 6] = ss;
  __syncthreads();
  if (threadIdx.x == 0) { sq[row] = red[0] + red[1] + red[2]; deg[row] = 1.f; }
}

// transpose + hi/lo split ALL weights in one launch; grid.z selects the weight
__global__ void k_wsplit_all(
    const float* __restrict__ W1, const float* __restrict__ W2, const float* __restrict__ W3,
    const float* __restrict__ Wc1, const float* __restrict__ Wc2,
    u16* __restrict__ W1th, u16* __restrict__ W1tl, u16* __restrict__ W2th, u16* __restrict__ W2tl,
    u16* __restrict__ W3th, u16* __restrict__ W3tl, u16* __restrict__ Wc1th, u16* __restrict__ Wc1tl,
    u16* __restrict__ Wc2th, u16* __restrict__ Wc2tl) {
  const float* W; u16 *Th, *Tl; int K, N;
  switch (blockIdx.z) {
    case 0: W = W1;  Th = W1th;  Tl = W1tl;  K = Fn;      N = Hn;  break;
    case 1: W = W2;  Th = W2th;  Tl = W2tl;  K = Hn;      N = Hn;  break;
    case 2: W = W3;  Th = W3th;  Tl = W3tl;  K = Hn;      N = Hn;  break;
    case 3: W = Wc1; Th = Wc1th; Tl = Wc1tl; K = Hn + Fn; N = 128; break;
    default: W = Wc2; Th = Wc2th; Tl = Wc2tl; K = 128;    N = Cn;  break;
  }
  int k0 = blockIdx.y * 32, n0 = blockIdx.x * 32;
  if (k0 >= K || n0 >= N) return;
  __shared__ float t[32][33];
  int tx = threadIdx.x & 31, ty = threadIdx.x >> 5;
  for (int p = 0; p < 32; p += 8) {
    int k = k0 + ty + p, n = n0 + tx;
    t[ty + p][tx] = (k < K && n < N) ? W[(size_t)k * N + n] : 0.f;
  }
  __syncthreads();
  for (int p = 0; p < 32; p += 8) {
    int n = n0 + ty + p, k = k0 + tx;
    if (n < N && k < K) {
      float x = t[tx][ty + p];
      __hip_bfloat16 h = __float2bfloat16(x);
      float hf = __bfloat162float(h);
      __hip_bfloat16 lo = __float2bfloat16(x - hf);
      Th[(size_t)n * K + k] = *reinterpret_cast<u16*>(&h);
      Tl[(size_t)n * K + k] = *reinterpret_cast<u16*>(&lo);
    }
  }
}

// ---------- single-bf16 MFMA Gram, 64×64 tiles, BK=128 (12 K-steps), XCD schedule ----------
__global__ __launch_bounds__(256) void k_gram(
    const u16* __restrict__ Ah, const double* __restrict__ sq, u64* __restrict__ part) {
  __shared__ union {
    u16 t[2][8192];     // [mat]: [kh*2048el + row*32el + col_el], 16 KB each (kh 0..3)
    float c[64 * 65];   // C tile (epilogue)
  } lds;
  const int tid = threadIdx.x;
  const int w = tid >> 6, l = tid & 63;

  // schedule decode: XCD x gets diag group-pair (x,x) + off-pairs {3x..3x+2} + half shared pair
  int xcd = blockIdx.x & 7;
  int s = blockIdx.x >> 3;           // 0..259
  int ti, tj;
  if (s < 36) {
    int rem = s, a_ = 0;
#pragma unroll 1
    while (rem >= 8 - a_) { rem -= 8 - a_; a_++; }
    ti = xcd * 8 + a_;
    tj = xcd * 8 + a_ + rem;
  } else {
    int sp = s - 36;
    int q = sp >> 6, r = sp & 63;
    int op, l64;
    if (q < 3) { op = xcd * 3 + q; l64 = r; }
    else       { op = 24 + (xcd >> 1); l64 = ((xcd & 1) << 5) | r; }
    int rem = op, g = 0;
#pragma unroll 1
    while (rem >= 7 - g) { rem -= 7 - g; g++; }
    int gi = g, gj = g + 1 + rem;
    ti = gi * 8 + (l64 >> 3);
    tj = gj * 8 + (l64 & 7);
  }
  const int rA0 = ti * 64, rB0 = tj * 64;
  const int isDiag = (ti == tj);

  f32x4 acc[2][2];
  const f32x4 fz = {0.f, 0.f, 0.f, 0.f};
#pragma unroll
  for (int i = 0; i < 2; i++)
#pragma unroll
    for (int j = 0; j < 2; j++) acc[i][j] = fz;

  const u16* mats[2] = { Ah + (size_t)rA0 * Fn, Ah + (size_t)rB0 * Fn };

  // staging: 32 segs of 1024 B (2 mats × 4 kh × 4 sg); seg covers 16 rows × 64 B
  auto stage = [&](int k0) {
#pragma unroll
    for (int q = 0; q < 8; q++) {
      int idx = w * 8 + q;                 // 0..31
      int mm = idx >> 4, kh = (idx >> 2) & 3, sg = idx & 3;
      int row = sg * 16 + (l >> 2);
      int colel = (l & 3) * 8;
      gld16(mats[mm] + (size_t)row * Fn + k0 + kh * 32 + colel,
            (char*)&lds.t[mm][0] + kh * 4096 + sg * 1024);
    }
  };

  const int cB = (l >> 4) * 16;
  const int fr16 = l & 15;

  stage(0);
  const int NT = Fn / GBK;   // 12
  for (int kt = 0; kt < NT; kt++) {
    __syncthreads();                 // drain staged loads
#pragma unroll
    for (int kh = 0; kh < 4; kh++) {
      short8 fa[2], fb[2];
#pragma unroll
      for (int i = 0; i < 2; i++) {
        int ar = (w >> 1) * 32 + i * 16 + fr16;
        fa[i] = *reinterpret_cast<const short8*>((const char*)&lds.t[0][0] + kh * 4096 + ar * 64 + cB);
        int br = (w & 1) * 32 + i * 16 + fr16;
        fb[i] = *reinterpret_cast<const short8*>((const char*)&lds.t[1][0] + kh * 4096 + br * 64 + cB);
      }
#pragma unroll
      for (int i = 0; i < 2; i++)
#pragma unroll
        for (int j = 0; j < 2; j++)
          acc[i][j] = __builtin_amdgcn_mfma_f32_16x16x32_bf16(fa[i], fb[j], acc[i][j], 0, 0, 0);
    }
    __syncthreads();                 // all reads done before next stage overwrites
    if (kt + 1 < NT) stage((kt + 1) * GBK);
  }

  // epilogue: C tile to LDS
  const int fr = l & 15, fq = l >> 4;
#pragma unroll
  for (int i = 0; i < 2; i++) {
    int r0 = (w >> 1) * 32 + i * 16 + fq * 4;
#pragma unroll
    for (int j = 0; j < 2; j++) {
      int c0 = (w & 1) * 32 + j * 16 + fr;
#pragma unroll
      for (int gg = 0; gg < 4; gg++)
        lds.c[(r0 + gg) * 65 + c0] = acc[i][j][gg];
    }
  }
  __syncthreads();

  u64 top[8];
#pragma unroll
  for (int k = 0; k < 8; k++) top[k] = ~0ull;
  if (tid < 64) {
    int grow = rA0 + tid;
    float sqr = (float)sq[grow];
#pragma unroll 1
    for (int c = 0; c < 64; c++) {
      int gc = rB0 + c;
      if (gc == grow) continue;
      float gv = lds.c[tid * 65 + c];
      float d2 = fmaxf(sqr + (float)sq[gc] - 2.f * gv, 0.f);
      u64 key = ((u64)__float_as_uint(d2) << 32) | (u32)gc;
      if (key < top[7]) {
        top[7] = key;
#pragma unroll
        for (int k = 7; k > 0; k--)
          if (top[k] < top[k - 1]) { u64 tmp = top[k]; top[k] = top[k - 1]; top[k - 1] = tmp; }
      }
    }
    u64* dst = part + ((size_t)grow * 64 + tj) * 8;
#pragma unroll
    for (int k = 0; k < 8; k++) dst[k] = top[k];
  } else if (tid < 128 && !isDiag) {
    int cl = tid - 64;
    int gcol = rB0 + cl;
    float sqc = (float)sq[gcol];
#pragma unroll 1
    for (int s2 = 0; s2 < 64; s2++) {
      float gv = lds.c[s2 * 65 + cl];
      int gr = rA0 + s2;
      float d2 = fmaxf(sqc + (float)sq[gr] - 2.f * gv, 0.f);
      u64 key = ((u64)__float_as_uint(d2) << 32) | (u32)gr;
      if (key < top[7]) {
        top[7] = key;
#pragma unroll
        for (int k = 7; k > 0; k--)
          if (top[k] < top[k - 1]) { u64 tmp = top[k]; top[k] = top[k - 1]; top[k - 1] = tmp; }
      }
    }
    u64* dst = part + ((size_t)gcol * 64 + ti) * 8;
#pragma unroll
    for (int k = 0; k < 8; k++) dst[k] = top[k];
  }
}

// merge 512 partial candidates per row -> top-NCAND approx candidates (high occupancy)
__global__ __launch_bounds__(256) void k_candmerge(const u64* __restrict__ part,
                                                   int* __restrict__ cand) {
  int row = blockIdx.x * 4 + (threadIdx.x >> 6);
  int l = threadIdx.x & 63;
  const u64* p = part + (size_t)row * 512 + (size_t)l * 8;
  u64 e[8];
#pragma unroll
  for (int k = 0; k < 8; k++) e[k] = p[k];
#pragma unroll 1
  for (int rnd = 0; rnd < NCAND; rnd++) {
    u64 m = e[0];
#pragma unroll
    for (int k = 1; k < 8; k++) m = e[k] < m ? e[k] : m;
#pragma unroll
    for (int off = 32; off; off >>= 1) {
      u64 o = __shfl_xor(m, off);
      m = o < m ? o : m;
    }
    if (l == 0) cand[row * NCAND + rnd] = (int)(u32)m;
#pragma unroll
    for (int k = 0; k < 8; k++)
      if (e[k] == m) e[k] = ~0ull;
  }
}

// exact f64 re-rank of NCAND candidates (+ noise tie-break) -> knn[row][7]; fused deg scatter.
// float4-vectorized row loads; xr (own row, BN'd, f64) held in registers.
__global__ __launch_bounds__(256) void k_rerank(
    const float* __restrict__ feat, const double* __restrict__ A64,
    const double* __restrict__ C64, const double* __restrict__ sq,
    const float* __restrict__ noise, const int* __restrict__ cand,
    int* __restrict__ knn, float* __restrict__ deg) {
  int row = blockIdx.x;
  int w = threadIdx.x >> 6, l = threadIdx.x & 63;
  double xr[24];
  const float* fr = feat + (size_t)row * Fn;
#pragma unroll
  for (int i = 0; i < 6; i++) {
    int e = (l + 64 * i) * 4;
    float4 xv = *reinterpret_cast<const float4*>(fr + e);
    xr[i * 4 + 0] = fma((double)xv.x, A64[e + 0], C64[e + 0]);
    xr[i * 4 + 1] = fma((double)xv.y, A64[e + 1], C64[e + 1]);
    xr[i * 4 + 2] = fma((double)xv.z, A64[e + 2], C64[e + 2]);
    xr[i * 4 + 3] = fma((double)xv.w, A64[e + 3], C64[e + 3]);
  }
  __shared__ double dots[NCAND];
  for (int m = w; m < NCAND; m += 4) {
    int c = cand[row * NCAND + m];
    const float* fc = feat + (size_t)c * Fn;
    double s = 0.0;
#pragma unroll
    for (int i = 0; i < 6; i++) {
      int e = (l + 64 * i) * 4;
      float4 yv = *reinterpret_cast<const float4*>(fc + e);
      s = fma(xr[i * 4 + 0], fma((double)yv.x, A64[e + 0], C64[e + 0]), s);
      s = fma(xr[i * 4 + 1], fma((double)yv.y, A64[e + 1], C64[e + 1]), s);
      s = fma(xr[i * 4 + 2], fma((double)yv.z, A64[e + 2], C64[e + 2]), s);
      s = fma(xr[i * 4 + 3], fma((double)yv.w, A64[e + 3], C64[e + 3]), s);
    }
#pragma unroll
    for (int off = 32; off; off >>= 1) s += __shfl_xor(s, off);
    if (l == 0) dots[m] = s;
  }
  __syncthreads();
  if (threadIdx.x == 0) {
    double sr = sq[row];
    double bd[Kn]; int bi7[Kn];
#pragma unroll
    for (int k = 0; k < Kn; k++) { bd[k] = 1e300; bi7[k] = 0; }
#pragma unroll 1
    for (int m = 0; m < NCAND; m++) {
      int c = cand[row * NCAND + m];
      double d2 = sr + sq[c] - 2.0 * dots[m];
      d2 = d2 > 0.0 ? d2 : 0.0;
      double d = sqrt(d2) + (double)noise[(size_t)row * Bn + c] * 1e-6;
      if (d < bd[Kn - 1]) {
        bd[Kn - 1] = d; bi7[Kn - 1] = c;
#pragma unroll
        for (int k = Kn - 1; k > 0; k--)
          if (bd[k] < bd[k - 1]) {
            double td = bd[k]; bd[k] = bd[k - 1]; bd[k - 1] = td;
            int ti = bi7[k]; bi7[k] = bi7[k - 1]; bi7[k - 1] = ti;
          }
      }
    }
#pragma unroll
    for (int k = 0; k < Kn; k++) {
      knn[row * Kn + k] = bi7[k];
      atomicAdd(&deg[bi7[k]], 1.f);
    }
  }
}

__global__ void k_dinv(const float* __restrict__ deg, float* __restrict__ dinv) {
  int i = blockIdx.x * 256 + threadIdx.x;
  if (i < Bn) dinv[i] = rsqrtf(deg[i]);
}

// ---------- GCN scatter ----------
__global__ void k_aggsc(const float* __restrict__ h, const int* __restrict__ knn,
                        const float* __restrict__ dinv, float* __restrict__ out) {
  int s = blockIdx.x, f = threadIdx.x;
  float hv = h[(size_t)s * Hn + f] * dinv[s];
#pragma unroll
  for (int k = 0; k < Kn; k++) {
    int t = knn[s * Kn + k];
    atomicAdd(&out[(size_t)t * Hn + f], dinv[t] * hv);
  }
}

// BN (+relu) then hi/lo bf16 split; 8 elems/thread
__global__ void k_bnact_split(const float* __restrict__ x, const float* __restrict__ g,
                              const float* __restrict__ b, const float* __restrict__ m,
                              const float* __restrict__ v, int relu,
                              u16* __restrict__ oh, u16* __restrict__ ol) {
  size_t i8 = ((size_t)blockIdx.x * 256 + threadIdx.x) * 8;
  int c0 = (int)(i8 & (Hn - 1));
  float4 a = *reinterpret_cast<const float4*>(x + i8);
  float4 bb = *reinterpret_cast<const float4*>(x + i8 + 4);
  float xs[8] = {a.x, a.y, a.z, a.w, bb.x, bb.y, bb.z, bb.w};
  short8 hv, lv;
#pragma unroll
  for (int k = 0; k < 8; k++) {
    int c = c0 + k;
    float val = (xs[k] - m[c]) * rsqrtf(v[c] + 1e-5f) * g[c] + b[c];
    if (relu) val = fmaxf(val, 0.f);
    __hip_bfloat16 h = __float2bfloat16(val);
    float hf = __bfloat162float(h);
    __hip_bfloat16 lo = __float2bfloat16(val - hf);
    hv[k] = (short)*reinterpret_cast<u16*>(&h);
    lv[k] = (short)*reinterpret_cast<u16*>(&lo);
  }
  *reinterpret_cast<short8*>(oh + i8) = hv;
  *reinterpret_cast<short8*>(ol + i8) = lv;
}

// ---------- bf16-split MFMA GEMM (double-buffered): C[M×N] f32 = [A1|A2] @ W ----------
// ep: 0 none, 1 +bias, 2 +bias+relu, 3 dual-write (C=raw, C2=dinv²·raw+bias),
//     4 bias+relu then bf16 hi/lo split to OH/OL. Stores guarded by cg<N.
__global__ __launch_bounds__(256) void k_mgemm(
    const u16* __restrict__ Ah1, const u16* __restrict__ Al1, int lda1,
    const u16* __restrict__ Ah2, const u16* __restrict__ Al2, int lda2, int Ksplit,
    const u16* __restrict__ Wth, const u16* __restrict__ Wtl,
    const float* __restrict__ bias, float* __restrict__ C, int N, int K, int ep,
    float* __restrict__ C2, const float* __restrict__ dinvp,
    u16* __restrict__ OH, u16* __restrict__ OL) {
  __shared__ u16 tA[2][2][4096];
  __shared__ u16 tB[2][2][4096];
  const int tid = threadIdx.x;
  const int w = tid >> 6, l = tid & 63;
  const int m0 = blockIdx.y * 64, n0 = blockIdx.x * 64;
  const int fr = l & 15, fq = l >> 4;

  f32x4 acc[2][2];
  const f32x4 fz = {0.f, 0.f, 0.f, 0.f};
#pragma unroll
  for (int i = 0; i < 2; i++)
#pragma unroll
    for (int j = 0; j < 2; j++) acc[i][j] = fz;

  auto stage = [&](int buf, int k0) {
#pragma unroll
    for (int q = 0; q < 2; q++) {
      int s = w * 2 + q;
      int kg = k0 + s * 8;
      const u16* ah; const u16* al; int ld; int kk = kg;
      if (kg < Ksplit) { ah = Ah1; al = Al1; ld = lda1; }
      else             { ah = Ah2; al = Al2; ld = lda2; kk = kg - Ksplit; }
      gld16(ah + (size_t)(m0 + l) * ld + kk, (char*)&tA[buf][0][0] + s * 1024);
      gld16(al + (size_t)(m0 + l) * ld + kk, (char*)&tA[buf][1][0] + s * 1024);
      gld16(Wth + (size_t)(n0 + l) * K + kg, (char*)&tB[buf][0][0] + s * 1024);
      gld16(Wtl + (size_t)(n0 + l) * K + kg, (char*)&tB[buf][1][0] + s * 1024);
    }
  };

  stage(0, 0);
  const int NT = K / 64;
  int cur = 0;
  for (int kt = 0; kt < NT; kt++) {
    __syncthreads();
    if (kt + 1 < NT) stage(cur ^ 1, (kt + 1) * 64);
#pragma unroll
    for (int kh = 0; kh < 2; kh++) {
      const int kb = (kh * 4 + fq) * 1024;
      short8 fa[2][2], fb[2][2];
#pragma unroll
      for (int i = 0; i < 2; i++) {
        int ar = (w >> 1) * 32 + i * 16 + fr;
        fa[0][i] = *reinterpret_cast<const short8*>((const char*)&tA[cur][0][0] + kb + ar * 16);
        fa[1][i] = *reinterpret_cast<const short8*>((const char*)&tA[cur][1][0] + kb + ar * 16);
        int br = (w & 1) * 32 + i * 16 + fr;
        fb[0][i] = *reinterpret_cast<const short8*>((const char*)&tB[cur][0][0] + kb + br * 16);
        fb[1][i] = *reinterpret_cast<const short8*>((const char*)&tB[cur][1][0] + kb + br * 16);
      }
#pragma unroll
      for (int i = 0; i < 2; i++)
#pragma unroll
        for (int j = 0; j < 2; j++) {
          acc[i][j] = __builtin_amdgcn_mfma_f32_16x16x32_bf16(fa[1][i], fb[0][j], acc[i][j], 0, 0, 0);
          acc[i][j] = __builtin_amdgcn_mfma_f32_16x16x32_bf16(fa[0][i], fb[1][j], acc[i][j], 0, 0, 0);
          acc[i][j] = __builtin_amdgcn_mfma_f32_16x16x32_bf16(fa[0][i], fb[0][j], acc[i][j], 0, 0, 0);
        }
    }
    cur ^= 1;
  }

#pragma unroll
  for (int i = 0; i < 2; i++) {
    int rg0 = m0 + (w >> 1) * 32 + i * 16 + fq * 4;
#pragma unroll
    for (int j = 0; j < 2; j++) {
      int cg = n0 + (w & 1) * 32 + j * 16 + fr;
      if (cg >= N) continue;
      float bv = (ep >= 1) ? bias[cg] : 0.f;
#pragma unroll
      for (int g = 0; g < 4; g++) {
        float raw = acc[i][j][g];
        size_t idx = (size_t)(rg0 + g) * N + cg;
        if (ep == 3) {
          float di = dinvp[rg0 + g];
          C[idx] = raw;
          C2[idx] = di * di * raw + bv;
        } else if (ep == 4) {
          float val = fmaxf(raw + bv, 0.f);
          __hip_bfloat16 h = __float2bfloat16(val);
          float hf = __bfloat162float(h);
          __hip_bfloat16 lo = __float2bfloat16(val - hf);
          OH[idx] = *reinterpret_cast<u16*>(&h);
          OL[idx] = *reinterpret_cast<u16*>(&lo);
        } else {
          float val = raw + bv;
          if (ep == 2) val = fmaxf(val, 0.f);
          C[idx] = val;
        }
      }
    }
  }
}

extern "C" void kernel_launch(void* const* d_in, const int* in_sizes, int n_in,
                              void* d_out, int out_size, void* d_ws, size_t ws_size,
                              hipStream_t stream) {
  const float* feat  = (const float*)d_in[0];
  const float* noise = (const float*)d_in[1];
  const float* bnf_g = (const float*)d_in[2];
  const float* bnf_b = (const float*)d_in[3];
  const float* bnf_m = (const float*)d_in[4];
  const float* bnf_v = (const float*)d_in[5];
  const float* W1 = (const float*)d_in[6];
  const float* b1 = (const float*)d_in[7];
  const float* W2 = (const float*)d_in[8];
  const float* b2 = (const float*)d_in[9];
  const float* W3 = (const float*)d_in[10];
  const float* b3 = (const float*)d_in[11];
  const float* bn1_g = (const float*)d_in[12];
  const float* bn1_b = (const float*)d_in[13];
  const float* bn1_m = (const float*)d_in[14];
  const float* bn1_v = (const float*)d_in[15];
  const float* bn2_g = (const float*)d_in[16];
  const float* bn2_b = (const float*)d_in[17];
  const float* bn2_m = (const float*)d_in[18];
  const float* bn2_v = (const float*)d_in[19];
  const float* bn3_g = (const float*)d_in[20];
  const float* bn3_b = (const float*)d_in[21];
  const float* bn3_m = (const float*)d_in[22];
  const float* bn3_v = (const float*)d_in[23];
  const float* Wc1 = (const float*)d_in[24];
  const float* bc1 = (const float*)d_in[25];
  const float* Wc2 = (const float*)d_in[26];
  const float* bc2 = (const float*)d_in[27];
  float* outp = (float*)d_out;

  char* w = (char*)d_ws;
  size_t off = 0;
  auto alloc = [&](size_t n) { void* p = w + off; off = (off + n + 255) & ~(size_t)255; return p; };
  u16*    Ahb  = (u16*)   alloc((size_t)Bn * Fn * 2);
  u16*    Alb  = (u16*)   alloc((size_t)Bn * Fn * 2);
  double* A64  = (double*)alloc(Fn * 8);
  double* C64  = (double*)alloc(Fn * 8);
  double* sq   = (double*)alloc(Bn * 8);
  u64*    part = (u64*)   alloc((size_t)Bn * 64 * 8 * 8);
  int*    cand = (int*)   alloc((size_t)Bn * NCAND * 4);
  int*    knn  = (int*)   alloc((size_t)Bn * Kn * 4);
  float*  deg  = (float*) alloc(Bn * 4);
  float*  dinv = (float*) alloc(Bn * 4);
  float*  g1   = (float*) alloc((size_t)Bn * Hn * 4);
  float*  g2   = (float*) alloc((size_t)Bn * Hn * 4);
  u16*    sh   = (u16*)   alloc((size_t)Bn * Hn * 2);
  u16*    sl   = (u16*)   alloc((size_t)Bn * Hn * 2);
  u16*    hidh = (u16*)   alloc((size_t)Bn * 128 * 2);
  u16*    hidl = (u16*)   alloc((size_t)Bn * 128 * 2);
  u16*    W1th = (u16*)   alloc((size_t)Fn * Hn * 2);
  u16*    W1tl = (u16*)   alloc((size_t)Fn * Hn * 2);
  u16*    W2th = (u16*)   alloc((size_t)Hn * Hn * 2);
  u16*    W2tl = (u16*)   alloc((size_t)Hn * Hn * 2);
  u16*    W3th = (u16*)   alloc((size_t)Hn * Hn * 2);
  u16*    W3tl = (u16*)   alloc((size_t)Hn * Hn * 2);
  u16*    Wc1th= (u16*)   alloc((size_t)(Hn + Fn) * 128 * 2);
  u16*    Wc1tl= (u16*)   alloc((size_t)(Hn + Fn) * 128 * 2);
  u16*    Wc2th= (u16*)   alloc((size_t)64 * 128 * 2);
  u16*    Wc2tl= (u16*)   alloc((size_t)64 * 128 * 2);
  (void)ws_size; (void)in_sizes; (void)n_in; (void)out_size;

  k_prep<<<(Fn + 255) / 256, 256, 0, stream>>>(bnf_g, bnf_b, bnf_m, bnf_v, A64, C64);
  k_bnsplit<<<Bn, Fn / 8, 0, stream>>>(feat, A64, C64, Ahb, Alb, sq, deg);
  k_wsplit_all<<<dim3(8, 56, 5), 256, 0, stream>>>(W1, W2, W3, Wc1, Wc2,
                                                   W1th, W1tl, W2th, W2tl, W3th, W3tl,
                                                   Wc1th, Wc1tl, Wc2th, Wc2tl);

  k_gram<<<2080, 256, 0, stream>>>(Ahb, sq, part);
  k_candmerge<<<Bn / 4, 256, 0, stream>>>(part, cand);
  k_rerank<<<Bn, 256, 0, stream>>>(feat, A64, C64, sq, noise, cand, knn, deg);
  k_dinv<<<(Bn + 255) / 256, 256, 0, stream>>>(deg, dinv);

  dim3 gm(Hn / 64, Bn / 64);
  // layer 1 (ep=3: g1 = h raw, g2 = di²h + b1)
  k_mgemm<<<gm, 256, 0, stream>>>(Ahb, Alb, Fn, Ahb, Alb, Fn, Fn, W1th, W1tl, b1, g1, Hn, Fn, 3,
                                  g2, dinv, nullptr, nullptr);
  k_aggsc<<<Bn, Hn, 0, stream>>>(g1, knn, dinv, g2);
  k_bnact_split<<<(Bn * Hn) / (256 * 8), 256, 0, stream>>>(g2, bn1_g, bn1_b, bn1_m, bn1_v, 1, sh, sl);
  // layer 2
  k_mgemm<<<gm, 256, 0, stream>>>(sh, sl, Hn, sh, sl, Hn, Hn, W2th, W2tl, b2, g1, Hn, Hn, 3,
                                  g2, dinv, nullptr, nullptr);
  k_aggsc<<<Bn, Hn, 0, stream>>>(g1, knn, dinv, g2);
  k_bnact_split<<<(Bn * Hn) / (256 * 8), 256, 0, stream>>>(g2, bn2_g, bn2_b, bn2_m, bn2_v, 1, sh, sl);
  // layer 3
  k_mgemm<<<gm, 256, 0, stream>>>(sh, sl, Hn, sh, sl, Hn, Hn, W3th, W3tl, b3, g1, Hn, Hn, 3,
                                  g2, dinv, nullptr, nullptr);
  k_aggsc<<<Bn, Hn, 0, stream>>>(g1, knn, dinv, g2);
  k_bnact_split<<<(Bn * Hn) / (256 * 8), 256, 0, stream>>>(g2, bn3_g, bn3_b, bn3_m, bn3_v, 0, sh, sl);
  // classifier1: comb = [h3 | x], ep=4 -> bf16-split hid
  k_mgemm<<<dim3(128 / 64, Bn / 64), 256, 0, stream>>>(sh, sl, Hn, Ahb, Alb, Fn, Hn,
                                                       Wc1th, Wc1tl, bc1, nullptr, 128, Hn + Fn, 4,
                                                       nullptr, nullptr, hidh, hidl);
  // classifier2: MFMA, N=38 guarded
  k_mgemm<<<dim3(1, Bn / 64), 256, 0, stream>>>(hidh, hidl, 128, hidh, hidl, 128, 128,
                                                Wc2th, Wc2tl, bc2, outp, Cn, 128, 1,
                                                nullptr, nullptr, nullptr, nullptr);
}

// Round 15
// 603.745 us; speedup vs baseline: 1.0027x; 1.0027x over previous
//
#include <hip/hip_runtime.h>
#include <hip/hip_bf16.h>
#include <math.h>

#define Bn 4096
#define Fn 1536
#define Hn 256
#define Cn 38
#define Kn 7
#define GBK 64
#define NCAND 12

typedef __attribute__((ext_vector_type(8))) short short8;
typedef __attribute__((ext_vector_type(4))) float f32x4;
typedef unsigned long long u64;
typedef unsigned int u32;
typedef unsigned short u16;

__device__ __forceinline__ void gld16(const void* g, void* l) {
  __builtin_amdgcn_global_load_lds((const __attribute__((address_space(1))) unsigned int*)g,
                                   (__attribute__((address_space(3))) unsigned int*)l, 16, 0, 0);
}

// ---------- BN param prep (f64): x = feat*A + C ----------
__global__ void k_prep(const float* __restrict__ g, const float* __restrict__ b,
                       const float* __restrict__ m, const float* __restrict__ v,
                       double* __restrict__ A64, double* __restrict__ C64) {
  int f = blockIdx.x * 256 + threadIdx.x;
  if (f < Fn) {
    double rs = 1.0 / sqrt((double)v[f] + 1e-5);
    double a = (double)g[f] * rs;
    A64[f] = a;
    C64[f] = (double)b[f] - (double)m[f] * a;
  }
}

// Ah/Al = bf16 hi/lo split of BN(features); fused sq[row]; fused deg init.
__global__ void k_bnsplit(const float* __restrict__ feat, const double* __restrict__ A64,
                          const double* __restrict__ C64,
                          u16* __restrict__ Ah, u16* __restrict__ Al, double* __restrict__ sq,
                          float* __restrict__ deg) {
  int row = blockIdx.x;
  int f0 = threadIdx.x * 8;
  const float* fr = feat + (size_t)row * Fn + f0;
  float4 a = *reinterpret_cast<const float4*>(fr);
  float4 b = *reinterpret_cast<const float4*>(fr + 4);
  float xs[8] = {a.x, a.y, a.z, a.w, b.x, b.y, b.z, b.w};
  short8 hv, lv;
  double ss = 0.0;
#pragma unroll
  for (int k = 0; k < 8; k++) {
    double xd = fma((double)xs[k], A64[f0 + k], C64[f0 + k]);
    ss = fma(xd, xd, ss);
    float x = (float)xd;
    __hip_bfloat16 h = __float2bfloat16(x);
    float hf = __bfloat162float(h);
    __hip_bfloat16 lo = __float2bfloat16(x - hf);
    hv[k] = (short)*reinterpret_cast<u16*>(&h);
    lv[k] = (short)*reinterpret_cast<u16*>(&lo);
  }
  *reinterpret_cast<short8*>(Ah + (size_t)row * Fn + f0) = hv;
  *reinterpret_cast<short8*>(Al + (size_t)row * Fn + f0) = lv;
#pragma unroll
  for (int o = 32; o; o >>= 1) ss += __shfl_down(ss, o);
  __shared__ double red[3];
  if ((threadIdx.x & 63) == 0) red[threadIdx.x >> 6] = ss;
  __syncthreads();
  if (threadIdx.x == 0) { sq[row] = red[0] + red[1] + red[2]; deg[row] = 1.f; }
}

// transpose + hi/lo split ALL weights in one launch; grid.z selects the weight
__global__ void k_wsplit_all(
    const float* __restrict__ W1, const float* __restrict__ W2, const float* __restrict__ W3,
    const float* __restrict__ Wc1, const float* __restrict__ Wc2,
    u16* __restrict__ W1th, u16* __restrict__ W1tl, u16* __restrict__ W2th, u16* __restrict__ W2tl,
    u16* __restrict__ W3th, u16* __restrict__ W3tl, u16* __restrict__ Wc1th, u16* __restrict__ Wc1tl,
    u16* __restrict__ Wc2th, u16* __restrict__ Wc2tl) {
  const float* W; u16 *Th, *Tl; int K, N;
  switch (blockIdx.z) {
    case 0: W = W1;  Th = W1th;  Tl = W1tl;  K = Fn;      N = Hn;  break;
    case 1: W = W2;  Th = W2th;  Tl = W2tl;  K = Hn;      N = Hn;  break;
    case 2: W = W3;  Th = W3th;  Tl = W3tl;  K = Hn;      N = Hn;  break;
    case 3: W = Wc1; Th = Wc1th; Tl = Wc1tl; K = Hn + Fn; N = 128; break;
    default: W = Wc2; Th = Wc2th; Tl = Wc2tl; K = 128;    N = Cn;  break;
  }
  int k0 = blockIdx.y * 32, n0 = blockIdx.x * 32;
  if (k0 >= K || n0 >= N) return;
  __shared__ float t[32][33];
  int tx = threadIdx.x & 31, ty = threadIdx.x >> 5;
  for (int p = 0; p < 32; p += 8) {
    int k = k0 + ty + p, n = n0 + tx;
    t[ty + p][tx] = (k < K && n < N) ? W[(size_t)k * N + n] : 0.f;
  }
  __syncthreads();
  for (int p = 0; p < 32; p += 8) {
    int n = n0 + ty + p, k = k0 + tx;
    if (n < N && k < K) {
      float x = t[tx][ty + p];
      __hip_bfloat16 h = __float2bfloat16(x);
      float hf = __bfloat162float(h);
      __hip_bfloat16 lo = __float2bfloat16(x - hf);
      Th[(size_t)n * K + k] = *reinterpret_cast<u16*>(&h);
      Tl[(size_t)n * K + k] = *reinterpret_cast<u16*>(&lo);
    }
  }
}

// ---------- single-bf16 MFMA Gram, 64×64 tiles, XCD-exact group-pair schedule ----------
// Single-buffered, two barriers per K-step (round-12 proven config).
__global__ __launch_bounds__(256) void k_gram(
    const u16* __restrict__ Ah, const double* __restrict__ sq, u64* __restrict__ part) {
  __shared__ union {
    u16 t[2][4096];     // [mat]: [kh*2048 + row*32 + col_el], 8 KB each
    float c[64 * 65];   // C tile (epilogue)
  } lds;
  const int tid = threadIdx.x;
  const int w = tid >> 6, l = tid & 63;

  // schedule decode: XCD x gets diag group-pair (x,x) + off-pairs {3x..3x+2} + half shared pair
  int xcd = blockIdx.x & 7;
  int s = blockIdx.x >> 3;           // 0..259
  int ti, tj;
  if (s < 36) {
    int rem = s, a_ = 0;
#pragma unroll 1
    while (rem >= 8 - a_) { rem -= 8 - a_; a_++; }
    ti = xcd * 8 + a_;
    tj = xcd * 8 + a_ + rem;
  } else {
    int sp = s - 36;
    int q = sp >> 6, r = sp & 63;
    int op, l64;
    if (q < 3) { op = xcd * 3 + q; l64 = r; }
    else       { op = 24 + (xcd >> 1); l64 = ((xcd & 1) << 5) | r; }
    int rem = op, g = 0;
#pragma unroll 1
    while (rem >= 7 - g) { rem -= 7 - g; g++; }
    int gi = g, gj = g + 1 + rem;
    ti = gi * 8 + (l64 >> 3);
    tj = gj * 8 + (l64 & 7);
  }
  const int rA0 = ti * 64, rB0 = tj * 64;
  const int isDiag = (ti == tj);

  f32x4 acc[2][2];
  const f32x4 fz = {0.f, 0.f, 0.f, 0.f};
#pragma unroll
  for (int i = 0; i < 2; i++)
#pragma unroll
    for (int j = 0; j < 2; j++) acc[i][j] = fz;

  const u16* mats[2] = { Ah + (size_t)rA0 * Fn, Ah + (size_t)rB0 * Fn };

  auto stage = [&](int k0) {
#pragma unroll
    for (int q = 0; q < 4; q++) {
      int idx = w * 4 + q;
      int mm = idx >> 3, kh = (idx >> 2) & 1, sg = idx & 3;
      int row = sg * 16 + (l >> 2);
      int colel = (l & 3) * 8;
      gld16(mats[mm] + (size_t)row * Fn + k0 + kh * 32 + colel,
            (char*)&lds.t[mm][0] + kh * 4096 + sg * 1024);
    }
  };

  const int cB = (l >> 4) * 16;
  const int fr16 = l & 15;

  stage(0);
  const int NT = Fn / GBK;
  for (int kt = 0; kt < NT; kt++) {
    __syncthreads();
#pragma unroll
    for (int kh = 0; kh < 2; kh++) {
      short8 fa[2], fb[2];
#pragma unroll
      for (int i = 0; i < 2; i++) {
        int ar = (w >> 1) * 32 + i * 16 + fr16;
        fa[i] = *reinterpret_cast<const short8*>((const char*)&lds.t[0][0] + kh * 4096 + ar * 64 + cB);
        int br = (w & 1) * 32 + i * 16 + fr16;
        fb[i] = *reinterpret_cast<const short8*>((const char*)&lds.t[1][0] + kh * 4096 + br * 64 + cB);
      }
#pragma unroll
      for (int i = 0; i < 2; i++)
#pragma unroll
        for (int j = 0; j < 2; j++)
          acc[i][j] = __builtin_amdgcn_mfma_f32_16x16x32_bf16(fa[i], fb[j], acc[i][j], 0, 0, 0);
    }
    __syncthreads();
    if (kt + 1 < NT) stage((kt + 1) * GBK);
  }

  // epilogue: C tile to LDS
  const int fr = l & 15, fq = l >> 4;
#pragma unroll
  for (int i = 0; i < 2; i++) {
    int r0 = (w >> 1) * 32 + i * 16 + fq * 4;
#pragma unroll
    for (int j = 0; j < 2; j++) {
      int c0 = (w & 1) * 32 + j * 16 + fr;
#pragma unroll
      for (int gg = 0; gg < 4; gg++)
        lds.c[(r0 + gg) * 65 + c0] = acc[i][j][gg];
    }
  }
  __syncthreads();

  u64 top[8];
#pragma unroll
  for (int k = 0; k < 8; k++) top[k] = ~0ull;
  if (tid < 64) {
    int grow = rA0 + tid;
    float sqr = (float)sq[grow];
#pragma unroll 1
    for (int c = 0; c < 64; c++) {
      int gc = rB0 + c;
      if (gc == grow) continue;
      float gv = lds.c[tid * 65 + c];
      float d2 = fmaxf(sqr + (float)sq[gc] - 2.f * gv, 0.f);
      u64 key = ((u64)__float_as_uint(d2) << 32) | (u32)gc;
      if (key < top[7]) {
        top[7] = key;
#pragma unroll
        for (int k = 7; k > 0; k--)
          if (top[k] < top[k - 1]) { u64 tmp = top[k]; top[k] = top[k - 1]; top[k - 1] = tmp; }
      }
    }
    u64* dst = part + ((size_t)grow * 64 + tj) * 8;
#pragma unroll
    for (int k = 0; k < 8; k++) dst[k] = top[k];
  } else if (tid < 128 && !isDiag) {
    int cl = tid - 64;
    int gcol = rB0 + cl;
    float sqc = (float)sq[gcol];
#pragma unroll 1
    for (int s2 = 0; s2 < 64; s2++) {
      float gv = lds.c[s2 * 65 + cl];
      int gr = rA0 + s2;
      float d2 = fmaxf(sqc + (float)sq[gr] - 2.f * gv, 0.f);
      u64 key = ((u64)__float_as_uint(d2) << 32) | (u32)gr;
      if (key < top[7]) {
        top[7] = key;
#pragma unroll
        for (int k = 7; k > 0; k--)
          if (top[k] < top[k - 1]) { u64 tmp = top[k]; top[k] = top[k - 1]; top[k - 1] = tmp; }
      }
    }
    u64* dst = part + ((size_t)gcol * 64 + ti) * 8;
#pragma unroll
    for (int k = 0; k < 8; k++) dst[k] = top[k];
  }
}

// merge 512 partial candidates per row -> top-NCAND approx candidates (high occupancy)
__global__ __launch_bounds__(256) void k_candmerge(const u64* __restrict__ part,
                                                   int* __restrict__ cand) {
  int row = blockIdx.x * 4 + (threadIdx.x >> 6);
  int l = threadIdx.x & 63;
  const u64* p = part + (size_t)row * 512 + (size_t)l * 8;
  u64 e[8];
#pragma unroll
  for (int k = 0; k < 8; k++) e[k] = p[k];
#pragma unroll 1
  for (int rnd = 0; rnd < NCAND; rnd++) {
    u64 m = e[0];
#pragma unroll
    for (int k = 1; k < 8; k++) m = e[k] < m ? e[k] : m;
#pragma unroll
    for (int off = 32; off; off >>= 1) {
      u64 o = __shfl_xor(m, off);
      m = o < m ? o : m;
    }
    if (l == 0) cand[row * NCAND + rnd] = (int)(u32)m;
#pragma unroll
    for (int k = 0; k < 8; k++)
      if (e[k] == m) e[k] = ~0ull;
  }
}

// exact f64 re-rank of NCAND candidates (+ noise tie-break) -> knn[row][7]; fused deg scatter.
// float4-vectorized row loads; xr (own row, BN'd, f64) held in registers.
__global__ __launch_bounds__(256) void k_rerank(
    const float* __restrict__ feat, const double* __restrict__ A64,
    const double* __restrict__ C64, const double* __restrict__ sq,
    const float* __restrict__ noise, const int* __restrict__ cand,
    int* __restrict__ knn, float* __restrict__ deg) {
  int row = blockIdx.x;
  int w = threadIdx.x >> 6, l = threadIdx.x & 63;
  double xr[24];
  const float* fr = feat + (size_t)row * Fn;
#pragma unroll
  for (int i = 0; i < 6; i++) {
    int e = (l + 64 * i) * 4;
    float4 xv = *reinterpret_cast<const float4*>(fr + e);
    xr[i * 4 + 0] = fma((double)xv.x, A64[e + 0], C64[e + 0]);
    xr[i * 4 + 1] = fma((double)xv.y, A64[e + 1], C64[e + 1]);
    xr[i * 4 + 2] = fma((double)xv.z, A64[e + 2], C64[e + 2]);
    xr[i * 4 + 3] = fma((double)xv.w, A64[e + 3], C64[e + 3]);
  }
  __shared__ double dots[NCAND];
  for (int m = w; m < NCAND; m += 4) {
    int c = cand[row * NCAND + m];
    const float* fc = feat + (size_t)c * Fn;
    double s = 0.0;
#pragma unroll
    for (int i = 0; i < 6; i++) {
      int e = (l + 64 * i) * 4;
      float4 yv = *reinterpret_cast<const float4*>(fc + e);
      s = fma(xr[i * 4 + 0], fma((double)yv.x, A64[e + 0], C64[e + 0]), s);
      s = fma(xr[i * 4 + 1], fma((double)yv.y, A64[e + 1], C64[e + 1]), s);
      s = fma(xr[i * 4 + 2], fma((double)yv.z, A64[e + 2], C64[e + 2]), s);
      s = fma(xr[i * 4 + 3], fma((double)yv.w, A64[e + 3], C64[e + 3]), s);
    }
#pragma unroll
    for (int off = 32; off; off >>= 1) s += __shfl_xor(s, off);
    if (l == 0) dots[m] = s;
  }
  __syncthreads();
  if (threadIdx.x == 0) {
    double sr = sq[row];
    double bd[Kn]; int bi7[Kn];
#pragma unroll
    for (int k = 0; k < Kn; k++) { bd[k] = 1e300; bi7[k] = 0; }
#pragma unroll 1
    for (int m = 0; m < NCAND; m++) {
      int c = cand[row * NCAND + m];
      double d2 = sr + sq[c] - 2.0 * dots[m];
      d2 = d2 > 0.0 ? d2 : 0.0;
      double d = sqrt(d2) + (double)noise[(size_t)row * Bn + c] * 1e-6;
      if (d < bd[Kn - 1]) {
        bd[Kn - 1] = d; bi7[Kn - 1] = c;
#pragma unroll
        for (int k = Kn - 1; k > 0; k--)
          if (bd[k] < bd[k - 1]) {
            double td = bd[k]; bd[k] = bd[k - 1]; bd[k - 1] = td;
            int ti = bi7[k]; bi7[k] = bi7[k - 1]; bi7[k - 1] = ti;
          }
      }
    }
#pragma unroll
    for (int k = 0; k < Kn; k++) {
      knn[row * Kn + k] = bi7[k];
      atomicAdd(&deg[bi7[k]], 1.f);
    }
  }
}

__global__ void k_dinv(const float* __restrict__ deg, float* __restrict__ dinv) {
  int i = blockIdx.x * 256 + threadIdx.x;
  if (i < Bn) dinv[i] = rsqrtf(deg[i]);
}

// ---------- GCN scatter ----------
__global__ void k_aggsc(const float* __restrict__ h, const int* __restrict__ knn,
                        const float* __restrict__ dinv, float* __restrict__ out) {
  int s = blockIdx.x, f = threadIdx.x;
  float hv = h[(size_t)s * Hn + f] * dinv[s];
#pragma unroll
  for (int k = 0; k < Kn; k++) {
    int t = knn[s * Kn + k];
    atomicAdd(&out[(size_t)t * Hn + f], dinv[t] * hv);
  }
}

// BN (+relu) then hi/lo bf16 split; 8 elems/thread
__global__ void k_bnact_split(const float* __restrict__ x, const float* __restrict__ g,
                              const float* __restrict__ b, const float* __restrict__ m,
                              const float* __restrict__ v, int relu,
                              u16* __restrict__ oh, u16* __restrict__ ol) {
  size_t i8 = ((size_t)blockIdx.x * 256 + threadIdx.x) * 8;
  int c0 = (int)(i8 & (Hn - 1));
  float4 a = *reinterpret_cast<const float4*>(x + i8);
  float4 bb = *reinterpret_cast<const float4*>(x + i8 + 4);
  float xs[8] = {a.x, a.y, a.z, a.w, bb.x, bb.y, bb.z, bb.w};
  short8 hv, lv;
#pragma unroll
  for (int k = 0; k < 8; k++) {
    int c = c0 + k;
    float val = (xs[k] - m[c]) * rsqrtf(v[c] + 1e-5f) * g[c] + b[c];
    if (relu) val = fmaxf(val, 0.f);
    __hip_bfloat16 h = __float2bfloat16(val);
    float hf = __bfloat162float(h);
    __hip_bfloat16 lo = __float2bfloat16(val - hf);
    hv[k] = (short)*reinterpret_cast<u16*>(&h);
    lv[k] = (short)*reinterpret_cast<u16*>(&lo);
  }
  *reinterpret_cast<short8*>(oh + i8) = hv;
  *reinterpret_cast<short8*>(ol + i8) = lv;
}

// ---------- bf16-split MFMA GEMM (double-buffered): C[M×N] f32 = [A1|A2] @ W ----------
// ep: 0 none, 1 +bias, 2 +bias+relu, 3 dual-write (C=raw, C2=dinv²·raw+bias),
//     4 bias+relu then bf16 hi/lo split to OH/OL. Stores guarded by cg<N.
__global__ __launch_bounds__(256) void k_mgemm(
    const u16* __restrict__ Ah1, const u16* __restrict__ Al1, int lda1,
    const u16* __restrict__ Ah2, const u16* __restrict__ Al2, int lda2, int Ksplit,
    const u16* __restrict__ Wth, const u16* __restrict__ Wtl,
    const float* __restrict__ bias, float* __restrict__ C, int N, int K, int ep,
    float* __restrict__ C2, const float* __restrict__ dinvp,
    u16* __restrict__ OH, u16* __restrict__ OL) {
  __shared__ u16 tA[2][2][4096];
  __shared__ u16 tB[2][2][4096];
  const int tid = threadIdx.x;
  const int w = tid >> 6, l = tid & 63;
  const int m0 = blockIdx.y * 64, n0 = blockIdx.x * 64;
  const int fr = l & 15, fq = l >> 4;

  f32x4 acc[2][2];
  const f32x4 fz = {0.f, 0.f, 0.f, 0.f};
#pragma unroll
  for (int i = 0; i < 2; i++)
#pragma unroll
    for (int j = 0; j < 2; j++) acc[i][j] = fz;

  auto stage = [&](int buf, int k0) {
#pragma unroll
    for (int q = 0; q < 2; q++) {
      int s = w * 2 + q;
      int kg = k0 + s * 8;
      const u16* ah; const u16* al; int ld; int kk = kg;
      if (kg < Ksplit) { ah = Ah1; al = Al1; ld = lda1; }
      else             { ah = Ah2; al = Al2; ld = lda2; kk = kg - Ksplit; }
      gld16(ah + (size_t)(m0 + l) * ld + kk, (char*)&tA[buf][0][0] + s * 1024);
      gld16(al + (size_t)(m0 + l) * ld + kk, (char*)&tA[buf][1][0] + s * 1024);
      gld16(Wth + (size_t)(n0 + l) * K + kg, (char*)&tB[buf][0][0] + s * 1024);
      gld16(Wtl + (size_t)(n0 + l) * K + kg, (char*)&tB[buf][1][0] + s * 1024);
    }
  };

  stage(0, 0);
  const int NT = K / GBK;
  int cur = 0;
  for (int kt = 0; kt < NT; kt++) {
    __syncthreads();
    if (kt + 1 < NT) stage(cur ^ 1, (kt + 1) * GBK);
#pragma unroll
    for (int kh = 0; kh < 2; kh++) {
      const int kb = (kh * 4 + fq) * 1024;
      short8 fa[2][2], fb[2][2];
#pragma unroll
      for (int i = 0; i < 2; i++) {
        int ar = (w >> 1) * 32 + i * 16 + fr;
        fa[0][i] = *reinterpret_cast<const short8*>((const char*)&tA[cur][0][0] + kb + ar * 16);
        fa[1][i] = *reinterpret_cast<const short8*>((const char*)&tA[cur][1][0] + kb + ar * 16);
        int br = (w & 1) * 32 + i * 16 + fr;
        fb[0][i] = *reinterpret_cast<const short8*>((const char*)&tB[cur][0][0] + kb + br * 16);
        fb[1][i] = *reinterpret_cast<const short8*>((const char*)&tB[cur][1][0] + kb + br * 16);
      }
#pragma unroll
      for (int i = 0; i < 2; i++)
#pragma unroll
        for (int j = 0; j < 2; j++) {
          acc[i][j] = __builtin_amdgcn_mfma_f32_16x16x32_bf16(fa[1][i], fb[0][j], acc[i][j], 0, 0, 0);
          acc[i][j] = __builtin_amdgcn_mfma_f32_16x16x32_bf16(fa[0][i], fb[1][j], acc[i][j], 0, 0, 0);
          acc[i][j] = __builtin_amdgcn_mfma_f32_16x16x32_bf16(fa[0][i], fb[0][j], acc[i][j], 0, 0, 0);
        }
    }
    cur ^= 1;
  }

#pragma unroll
  for (int i = 0; i < 2; i++) {
    int rg0 = m0 + (w >> 1) * 32 + i * 16 + fq * 4;
#pragma unroll
    for (int j = 0; j < 2; j++) {
      int cg = n0 + (w & 1) * 32 + j * 16 + fr;
      if (cg >= N) continue;
      float bv = (ep >= 1) ? bias[cg] : 0.f;
#pragma unroll
      for (int g = 0; g < 4; g++) {
        float raw = acc[i][j][g];
        size_t idx = (size_t)(rg0 + g) * N + cg;
        if (ep == 3) {
          float di = dinvp[rg0 + g];
          C[idx] = raw;
          C2[idx] = di * di * raw + bv;
        } else if (ep == 4) {
          float val = fmaxf(raw + bv, 0.f);
          __hip_bfloat16 h = __float2bfloat16(val);
          float hf = __bfloat162float(h);
          __hip_bfloat16 lo = __float2bfloat16(val - hf);
          OH[idx] = *reinterpret_cast<u16*>(&h);
          OL[idx] = *reinterpret_cast<u16*>(&lo);
        } else {
          float val = raw + bv;
          if (ep == 2) val = fmaxf(val, 0.f);
          C[idx] = val;
        }
      }
    }
  }
}

extern "C" void kernel_launch(void* const* d_in, const int* in_sizes, int n_in,
                              void* d_out, int out_size, void* d_ws, size_t ws_size,
                              hipStream_t stream) {
  const float* feat  = (const float*)d_in[0];
  const float* noise = (const float*)d_in[1];
  const float* bnf_g = (const float*)d_in[2];
  const float* bnf_b = (const float*)d_in[3];
  const float* bnf_m = (const float*)d_in[4];
  const float* bnf_v = (const float*)d_in[5];
  const float* W1 = (const float*)d_in[6];
  const float* b1 = (const float*)d_in[7];
  const float* W2 = (const float*)d_in[8];
  const float* b2 = (const float*)d_in[9];
  const float* W3 = (const float*)d_in[10];
  const float* b3 = (const float*)d_in[11];
  const float* bn1_g = (const float*)d_in[12];
  const float* bn1_b = (const float*)d_in[13];
  const float* bn1_m = (const float*)d_in[14];
  const float* bn1_v = (const float*)d_in[15];
  const float* bn2_g = (const float*)d_in[16];
  const float* bn2_b = (const float*)d_in[17];
  const float* bn2_m = (const float*)d_in[18];
  const float* bn2_v = (const float*)d_in[19];
  const float* bn3_g = (const float*)d_in[20];
  const float* bn3_b = (const float*)d_in[21];
  const float* bn3_m = (const float*)d_in[22];
  const float* bn3_v = (const float*)d_in[23];
  const float* Wc1 = (const float*)d_in[24];
  const float* bc1 = (const float*)d_in[25];
  const float* Wc2 = (const float*)d_in[26];
  const float* bc2 = (const float*)d_in[27];
  float* outp = (float*)d_out;

  char* w = (char*)d_ws;
  size_t off = 0;
  auto alloc = [&](size_t n) { void* p = w + off; off = (off + n + 255) & ~(size_t)255; return p; };
  u16*    Ahb  = (u16*)   alloc((size_t)Bn * Fn * 2);
  u16*    Alb  = (u16*)   alloc((size_t)Bn * Fn * 2);
  double* A64  = (double*)alloc(Fn * 8);
  double* C64  = (double*)alloc(Fn * 8);
  double* sq   = (double*)alloc(Bn * 8);
  u64*    part = (u64*)   alloc((size_t)Bn * 64 * 8 * 8);
  int*    cand = (int*)   alloc((size_t)Bn * NCAND * 4);
  int*    knn  = (int*)   alloc((size_t)Bn * Kn * 4);
  float*  deg  = (float*) alloc(Bn * 4);
  float*  dinv = (float*) alloc(Bn * 4);
  float*  g1   = (float*) alloc((size_t)Bn * Hn * 4);
  float*  g2   = (float*) alloc((size_t)Bn * Hn * 4);
  u16*    sh   = (u16*)   alloc((size_t)Bn * Hn * 2);
  u16*    sl   = (u16*)   alloc((size_t)Bn * Hn * 2);
  u16*    hidh = (u16*)   alloc((size_t)Bn * 128 * 2);
  u16*    hidl = (u16*)   alloc((size_t)Bn * 128 * 2);
  u16*    W1th = (u16*)   alloc((size_t)Fn * Hn * 2);
  u16*    W1tl = (u16*)   alloc((size_t)Fn * Hn * 2);
  u16*    W2th = (u16*)   alloc((size_t)Hn * Hn * 2);
  u16*    W2tl = (u16*)   alloc((size_t)Hn * Hn * 2);
  u16*    W3th = (u16*)   alloc((size_t)Hn * Hn * 2);
  u16*    W3tl = (u16*)   alloc((size_t)Hn * Hn * 2);
  u16*    Wc1th= (u16*)   alloc((size_t)(Hn + Fn) * 128 * 2);
  u16*    Wc1tl= (u16*)   alloc((size_t)(Hn + Fn) * 128 * 2);
  u16*    Wc2th= (u16*)   alloc((size_t)64 * 128 * 2);
  u16*    Wc2tl= (u16*)   alloc((size_t)64 * 128 * 2);
  (void)ws_size; (void)in_sizes; (void)n_in; (void)out_size;

  k_prep<<<(Fn + 255) / 256, 256, 0, stream>>>(bnf_g, bnf_b, bnf_m, bnf_v, A64, C64);
  k_bnsplit<<<Bn, Fn / 8, 0, stream>>>(feat, A64, C64, Ahb, Alb, sq, deg);
  k_wsplit_all<<<dim3(8, 56, 5), 256, 0, stream>>>(W1, W2, W3, Wc1, Wc2,
                                                   W1th, W1tl, W2th, W2tl, W3th, W3tl,
                                                   Wc1th, Wc1tl, Wc2th, Wc2tl);

  k_gram<<<2080, 256, 0, stream>>>(Ahb, sq, part);
  k_candmerge<<<Bn / 4, 256, 0, stream>>>(part, cand);
  k_rerank<<<Bn, 256, 0, stream>>>(feat, A64, C64, sq, noise, cand, knn, deg);
  k_dinv<<<(Bn + 255) / 256, 256, 0, stream>>>(deg, dinv);

  dim3 gm(Hn / 64, Bn / 64);
  // layer 1 (ep=3: g1 = h raw, g2 = di²h + b1)
  k_mgemm<<<gm, 256, 0, stream>>>(Ahb, Alb, Fn, Ahb, Alb, Fn, Fn, W1th, W1tl, b1, g1, Hn, Fn, 3,
                                  g2, dinv, nullptr, nullptr);
  k_aggsc<<<Bn, Hn, 0, stream>>>(g1, knn, dinv, g2);
  k_bnact_split<<<(Bn * Hn) / (256 * 8), 256, 0, stream>>>(g2, bn1_g, bn1_b, bn1_m, bn1_v, 1, sh, sl);
  // layer 2
  k_mgemm<<<gm, 256, 0, stream>>>(sh, sl, Hn, sh, sl, Hn, Hn, W2th, W2tl, b2, g1, Hn, Hn, 3,
                                  g2, dinv, nullptr, nullptr);
  k_aggsc<<<Bn, Hn, 0, stream>>>(g1, knn, dinv, g2);
  k_bnact_split<<<(Bn * Hn) / (256 * 8), 256, 0, stream>>>(g2, bn2_g, bn2_b, bn2_m, bn2_v, 1, sh, sl);
  // layer 3
  k_mgemm<<<gm, 256, 0, stream>>>(sh, sl, Hn, sh, sl, Hn, Hn, W3th, W3tl, b3, g1, Hn, Hn, 3,
                                  g2, dinv, nullptr, nullptr);
  k_aggsc<<<Bn, Hn, 0, stream>>>(g1, knn, dinv, g2);
  k_bnact_split<<<(Bn * Hn) / (256 * 8), 256, 0, stream>>>(g2, bn3_g, bn3_b, bn3_m, bn3_v, 0, sh, sl);
  // classifier1: comb = [h3 | x], ep=4 -> bf16-split hid
  k_mgemm<<<dim3(128 / 64, Bn / 64), 256, 0, stream>>>(sh, sl, Hn, Ahb, Alb, Fn, Hn,
                                                       Wc1th, Wc1tl, bc1, nullptr, 128, Hn + Fn, 4,
                                                       nullptr, nullptr, hidh, hidl);
  // classifier2: MFMA, N=38 guarded
  k_mgemm<<<dim3(1, Bn / 64), 256, 0, stream>>>(hidh, hidl, 128, hidh, hidl, 128, 128,
                                                Wc2th, Wc2tl, bc2, outp, Cn, 128, 1,
                                                nullptr, nullptr, nullptr, nullptr);
}

// Round 16
// 513.152 us; speedup vs baseline: 1.1797x; 1.1765x over previous
//
#include <hip/hip_runtime.h>
#include <hip/hip_bf16.h>
#include <math.h>

#define Bn 4096
#define Fn 1536
#define Hn 256
#define Cn 38
#define Kn 7
#define GBK 64
#define NCAND 12

typedef __attribute__((ext_vector_type(8))) short short8;
typedef __attribute__((ext_vector_type(4))) float f32x4;
typedef unsigned long long u64;
typedef unsigned int u32;
typedef unsigned short u16;

__device__ __forceinline__ void gld16(const void* g, void* l) {
  __builtin_amdgcn_global_load_lds((const __attribute__((address_space(1))) unsigned int*)g,
                                   (__attribute__((address_space(3))) unsigned int*)l, 16, 0, 0);
}

// ---------- BN param prep (f64): x = feat*A + C ----------
__global__ void k_prep(const float* __restrict__ g, const float* __restrict__ b,
                       const float* __restrict__ m, const float* __restrict__ v,
                       double* __restrict__ A64, double* __restrict__ C64) {
  int f = blockIdx.x * 256 + threadIdx.x;
  if (f < Fn) {
    double rs = 1.0 / sqrt((double)v[f] + 1e-5);
    double a = (double)g[f] * rs;
    A64[f] = a;
    C64[f] = (double)b[f] - (double)m[f] * a;
  }
}

// Ah/Al = bf16 hi/lo split of BN(features); fused sq[row]; fused deg init.
__global__ void k_bnsplit(const float* __restrict__ feat, const double* __restrict__ A64,
                          const double* __restrict__ C64,
                          u16* __restrict__ Ah, u16* __restrict__ Al, double* __restrict__ sq,
                          float* __restrict__ deg) {
  int row = blockIdx.x;
  int f0 = threadIdx.x * 8;
  const float* fr = feat + (size_t)row * Fn + f0;
  float4 a = *reinterpret_cast<const float4*>(fr);
  float4 b = *reinterpret_cast<const float4*>(fr + 4);
  float xs[8] = {a.x, a.y, a.z, a.w, b.x, b.y, b.z, b.w};
  short8 hv, lv;
  double ss = 0.0;
#pragma unroll
  for (int k = 0; k < 8; k++) {
    double xd = fma((double)xs[k], A64[f0 + k], C64[f0 + k]);
    ss = fma(xd, xd, ss);
    float x = (float)xd;
    __hip_bfloat16 h = __float2bfloat16(x);
    float hf = __bfloat162float(h);
    __hip_bfloat16 lo = __float2bfloat16(x - hf);
    hv[k] = (short)*reinterpret_cast<u16*>(&h);
    lv[k] = (short)*reinterpret_cast<u16*>(&lo);
  }
  *reinterpret_cast<short8*>(Ah + (size_t)row * Fn + f0) = hv;
  *reinterpret_cast<short8*>(Al + (size_t)row * Fn + f0) = lv;
#pragma unroll
  for (int o = 32; o; o >>= 1) ss += __shfl_down(ss, o);
  __shared__ double red[3];
  if ((threadIdx.x & 63) == 0) red[threadIdx.x >> 6] = ss;
  __syncthreads();
  if (threadIdx.x == 0) { sq[row] = red[0] + red[1] + red[2]; deg[row] = 1.f; }
}

// transpose + hi/lo split ALL weights in one launch; grid.z selects the weight
__global__ void k_wsplit_all(
    const float* __restrict__ W1, const float* __restrict__ W2, const float* __restrict__ W3,
    const float* __restrict__ Wc1, const float* __restrict__ Wc2,
    u16* __restrict__ W1th, u16* __restrict__ W1tl, u16* __restrict__ W2th, u16* __restrict__ W2tl,
    u16* __restrict__ W3th, u16* __restrict__ W3tl, u16* __restrict__ Wc1th, u16* __restrict__ Wc1tl,
    u16* __restrict__ Wc2th, u16* __restrict__ Wc2tl) {
  const float* W; u16 *Th, *Tl; int K, N;
  switch (blockIdx.z) {
    case 0: W = W1;  Th = W1th;  Tl = W1tl;  K = Fn;      N = Hn;  break;
    case 1: W = W2;  Th = W2th;  Tl = W2tl;  K = Hn;      N = Hn;  break;
    case 2: W = W3;  Th = W3th;  Tl = W3tl;  K = Hn;      N = Hn;  break;
    case 3: W = Wc1; Th = Wc1th; Tl = Wc1tl; K = Hn + Fn; N = 128; break;
    default: W = Wc2; Th = Wc2th; Tl = Wc2tl; K = 128;    N = Cn;  break;
  }
  int k0 = blockIdx.y * 32, n0 = blockIdx.x * 32;
  if (k0 >= K || n0 >= N) return;
  __shared__ float t[32][33];
  int tx = threadIdx.x & 31, ty = threadIdx.x >> 5;
  for (int p = 0; p < 32; p += 8) {
    int k = k0 + ty + p, n = n0 + tx;
    t[ty + p][tx] = (k < K && n < N) ? W[(size_t)k * N + n] : 0.f;
  }
  __syncthreads();
  for (int p = 0; p < 32; p += 8) {
    int n = n0 + ty + p, k = k0 + tx;
    if (n < N && k < K) {
      float x = t[tx][ty + p];
      __hip_bfloat16 h = __float2bfloat16(x);
      float hf = __bfloat162float(h);
      __hip_bfloat16 lo = __float2bfloat16(x - hf);
      Th[(size_t)n * K + k] = *reinterpret_cast<u16*>(&h);
      Tl[(size_t)n * K + k] = *reinterpret_cast<u16*>(&lo);
    }
  }
}

// ---------- single-bf16 MFMA Gram, 64×64 tiles, XCD-exact group-pair schedule ----------
// ROUND-12 EXACT k_gram: XOR swizzle (row&8 <-> 32B) on staging source + fragment read.
__global__ __launch_bounds__(256) void k_gram(
    const u16* __restrict__ Ah, const double* __restrict__ sq, u64* __restrict__ part) {
  __shared__ union {
    u16 t[2][4096];     // [mat]: [kh*2048 + row*32 + col_el], 8 KB each
    float c[64 * 65];   // C tile (epilogue)
  } lds;
  const int tid = threadIdx.x;
  const int w = tid >> 6, l = tid & 63;

  // schedule decode: XCD x gets diag group-pair (x,x) + off-pairs {3x..3x+2} + half shared pair
  int xcd = blockIdx.x & 7;
  int s = blockIdx.x >> 3;           // 0..259
  int ti, tj;
  if (s < 36) {
    int rem = s, a_ = 0;
#pragma unroll 1
    while (rem >= 8 - a_) { rem -= 8 - a_; a_++; }
    ti = xcd * 8 + a_;
    tj = xcd * 8 + a_ + rem;
  } else {
    int sp = s - 36;
    int q = sp >> 6, r = sp & 63;
    int op, l64;
    if (q < 3) { op = xcd * 3 + q; l64 = r; }
    else       { op = 24 + (xcd >> 1); l64 = ((xcd & 1) << 5) | r; }
    int rem = op, g = 0;
#pragma unroll 1
    while (rem >= 7 - g) { rem -= 7 - g; g++; }
    int gi = g, gj = g + 1 + rem;
    ti = gi * 8 + (l64 >> 3);
    tj = gj * 8 + (l64 & 7);
  }
  const int rA0 = ti * 64, rB0 = tj * 64;
  const int isDiag = (ti == tj);

  f32x4 acc[2][2];
  const f32x4 fz = {0.f, 0.f, 0.f, 0.f};
#pragma unroll
  for (int i = 0; i < 2; i++)
#pragma unroll
    for (int j = 0; j < 2; j++) acc[i][j] = fz;

  const u16* mats[2] = { Ah + (size_t)rA0 * Fn, Ah + (size_t)rB0 * Fn };

  auto stage = [&](int k0) {
#pragma unroll
    for (int q = 0; q < 4; q++) {
      int idx = w * 4 + q;
      int mm = idx >> 3, kh = (idx >> 2) & 1, sg = idx & 3;
      int row = sg * 16 + (l >> 2);
      int colel = ((l & 3) * 8) ^ ((row & 8) ? 16 : 0);   // inverse-swizzled source
      gld16(mats[mm] + (size_t)row * Fn + k0 + kh * 32 + colel,
            (char*)&lds.t[mm][0] + kh * 4096 + sg * 1024);
    }
  };

  const int cB = ((l >> 4) * 16) ^ ((l & 8) ? 32 : 0);    // swizzled read
  const int fr16 = l & 15;

  stage(0);
  const int NT = Fn / GBK;
  for (int kt = 0; kt < NT; kt++) {
    __syncthreads();
#pragma unroll
    for (int kh = 0; kh < 2; kh++) {
      short8 fa[2], fb[2];
#pragma unroll
      for (int i = 0; i < 2; i++) {
        int ar = (w >> 1) * 32 + i * 16 + fr16;
        fa[i] = *reinterpret_cast<const short8*>((const char*)&lds.t[0][0] + kh * 4096 + ar * 64 + cB);
        int br = (w & 1) * 32 + i * 16 + fr16;
        fb[i] = *reinterpret_cast<const short8*>((const char*)&lds.t[1][0] + kh * 4096 + br * 64 + cB);
      }
#pragma unroll
      for (int i = 0; i < 2; i++)
#pragma unroll
        for (int j = 0; j < 2; j++)
          acc[i][j] = __builtin_amdgcn_mfma_f32_16x16x32_bf16(fa[i], fb[j], acc[i][j], 0, 0, 0);
    }
    __syncthreads();
    if (kt + 1 < NT) stage((kt + 1) * GBK);
  }

  // epilogue: C tile to LDS
  const int fr = l & 15, fq = l >> 4;
#pragma unroll
  for (int i = 0; i < 2; i++) {
    int r0 = (w >> 1) * 32 + i * 16 + fq * 4;
#pragma unroll
    for (int j = 0; j < 2; j++) {
      int c0 = (w & 1) * 32 + j * 16 + fr;
#pragma unroll
      for (int gg = 0; gg < 4; gg++)
        lds.c[(r0 + gg) * 65 + c0] = acc[i][j][gg];
    }
  }
  __syncthreads();

  u64 top[8];
#pragma unroll
  for (int k = 0; k < 8; k++) top[k] = ~0ull;
  if (tid < 64) {
    int grow = rA0 + tid;
    float sqr = (float)sq[grow];
#pragma unroll 1
    for (int c = 0; c < 64; c++) {
      int gc = rB0 + c;
      if (gc == grow) continue;
      float gv = lds.c[tid * 65 + c];
      float d2 = fmaxf(sqr + (float)sq[gc] - 2.f * gv, 0.f);
      u64 key = ((u64)__float_as_uint(d2) << 32) | (u32)gc;
      if (key < top[7]) {
        top[7] = key;
#pragma unroll
        for (int k = 7; k > 0; k--)
          if (top[k] < top[k - 1]) { u64 tmp = top[k]; top[k] = top[k - 1]; top[k - 1] = tmp; }
      }
    }
    u64* dst = part + ((size_t)grow * 64 + tj) * 8;
#pragma unroll
    for (int k = 0; k < 8; k++) dst[k] = top[k];
  } else if (tid < 128 && !isDiag) {
    int cl = tid - 64;
    int gcol = rB0 + cl;
    float sqc = (float)sq[gcol];
#pragma unroll 1
    for (int s2 = 0; s2 < 64; s2++) {
      float gv = lds.c[s2 * 65 + cl];
      int gr = rA0 + s2;
      float d2 = fmaxf(sqc + (float)sq[gr] - 2.f * gv, 0.f);
      u64 key = ((u64)__float_as_uint(d2) << 32) | (u32)gr;
      if (key < top[7]) {
        top[7] = key;
#pragma unroll
        for (int k = 7; k > 0; k--)
          if (top[k] < top[k - 1]) { u64 tmp = top[k]; top[k] = top[k - 1]; top[k - 1] = tmp; }
      }
    }
    u64* dst = part + ((size_t)gcol * 64 + ti) * 8;
#pragma unroll
    for (int k = 0; k < 8; k++) dst[k] = top[k];
  }
}

// merge 512 partial candidates per row -> top-NCAND approx candidates (high occupancy)
__global__ __launch_bounds__(256) void k_candmerge(const u64* __restrict__ part,
                                                   int* __restrict__ cand) {
  int row = blockIdx.x * 4 + (threadIdx.x >> 6);
  int l = threadIdx.x & 63;
  const u64* p = part + (size_t)row * 512 + (size_t)l * 8;
  u64 e[8];
#pragma unroll
  for (int k = 0; k < 8; k++) e[k] = p[k];
#pragma unroll 1
  for (int rnd = 0; rnd < NCAND; rnd++) {
    u64 m = e[0];
#pragma unroll
    for (int k = 1; k < 8; k++) m = e[k] < m ? e[k] : m;
#pragma unroll
    for (int off = 32; off; off >>= 1) {
      u64 o = __shfl_xor(m, off);
      m = o < m ? o : m;
    }
    if (l == 0) cand[row * NCAND + rnd] = (int)(u32)m;
#pragma unroll
    for (int k = 0; k < 8; k++)
      if (e[k] == m) e[k] = ~0ull;
  }
}

// exact f64 re-rank of NCAND candidates (+ noise tie-break) -> knn[row][7]; fused deg scatter.
// float4-vectorized row loads; xr (own row, BN'd, f64) held in registers.
__global__ __launch_bounds__(256) void k_rerank(
    const float* __restrict__ feat, const double* __restrict__ A64,
    const double* __restrict__ C64, const double* __restrict__ sq,
    const float* __restrict__ noise, const int* __restrict__ cand,
    int* __restrict__ knn, float* __restrict__ deg) {
  int row = blockIdx.x;
  int w = threadIdx.x >> 6, l = threadIdx.x & 63;
  double xr[24];
  const float* fr = feat + (size_t)row * Fn;
#pragma unroll
  for (int i = 0; i < 6; i++) {
    int e = (l + 64 * i) * 4;
    float4 xv = *reinterpret_cast<const float4*>(fr + e);
    xr[i * 4 + 0] = fma((double)xv.x, A64[e + 0], C64[e + 0]);
    xr[i * 4 + 1] = fma((double)xv.y, A64[e + 1], C64[e + 1]);
    xr[i * 4 + 2] = fma((double)xv.z, A64[e + 2], C64[e + 2]);
    xr[i * 4 + 3] = fma((double)xv.w, A64[e + 3], C64[e + 3]);
  }
  __shared__ double dots[NCAND];
  for (int m = w; m < NCAND; m += 4) {
    int c = cand[row * NCAND + m];
    const float* fc = feat + (size_t)c * Fn;
    double s = 0.0;
#pragma unroll
    for (int i = 0; i < 6; i++) {
      int e = (l + 64 * i) * 4;
      float4 yv = *reinterpret_cast<const float4*>(fc + e);
      s = fma(xr[i * 4 + 0], fma((double)yv.x, A64[e + 0], C64[e + 0]), s);
      s = fma(xr[i * 4 + 1], fma((double)yv.y, A64[e + 1], C64[e + 1]), s);
      s = fma(xr[i * 4 + 2], fma((double)yv.z, A64[e + 2], C64[e + 2]), s);
      s = fma(xr[i * 4 + 3], fma((double)yv.w, A64[e + 3], C64[e + 3]), s);
    }
#pragma unroll
    for (int off = 32; off; off >>= 1) s += __shfl_xor(s, off);
    if (l == 0) dots[m] = s;
  }
  __syncthreads();
  if (threadIdx.x == 0) {
    double sr = sq[row];
    double bd[Kn]; int bi7[Kn];
#pragma unroll
    for (int k = 0; k < Kn; k++) { bd[k] = 1e300; bi7[k] = 0; }
#pragma unroll 1
    for (int m = 0; m < NCAND; m++) {
      int c = cand[row * NCAND + m];
      double d2 = sr + sq[c] - 2.0 * dots[m];
      d2 = d2 > 0.0 ? d2 : 0.0;
      double d = sqrt(d2) + (double)noise[(size_t)row * Bn + c] * 1e-6;
      if (d < bd[Kn - 1]) {
        bd[Kn - 1] = d; bi7[Kn - 1] = c;
#pragma unroll
        for (int k = Kn - 1; k > 0; k--)
          if (bd[k] < bd[k - 1]) {
            double td = bd[k]; bd[k] = bd[k - 1]; bd[k - 1] = td;
            int ti = bi7[k]; bi7[k] = bi7[k - 1]; bi7[k - 1] = ti;
          }
      }
    }
#pragma unroll
    for (int k = 0; k < Kn; k++) {
      knn[row * Kn + k] = bi7[k];
      atomicAdd(&deg[bi7[k]], 1.f);
    }
  }
}

__global__ void k_dinv(const float* __restrict__ deg, float* __restrict__ dinv) {
  int i = blockIdx.x * 256 + threadIdx.x;
  if (i < Bn) dinv[i] = rsqrtf(deg[i]);
}

// ---------- GCN scatter ----------
__global__ void k_aggsc(const float* __restrict__ h, const int* __restrict__ knn,
                        const float* __restrict__ dinv, float* __restrict__ out) {
  int s = blockIdx.x, f = threadIdx.x;
  float hv = h[(size_t)s * Hn + f] * dinv[s];
#pragma unroll
  for (int k = 0; k < Kn; k++) {
    int t = knn[s * Kn + k];
    atomicAdd(&out[(size_t)t * Hn + f], dinv[t] * hv);
  }
}

// BN (+relu) then hi/lo bf16 split; 8 elems/thread
__global__ void k_bnact_split(const float* __restrict__ x, const float* __restrict__ g,
                              const float* __restrict__ b, const float* __restrict__ m,
                              const float* __restrict__ v, int relu,
                              u16* __restrict__ oh, u16* __restrict__ ol) {
  size_t i8 = ((size_t)blockIdx.x * 256 + threadIdx.x) * 8;
  int c0 = (int)(i8 & (Hn - 1));
  float4 a = *reinterpret_cast<const float4*>(x + i8);
  float4 bb = *reinterpret_cast<const float4*>(x + i8 + 4);
  float xs[8] = {a.x, a.y, a.z, a.w, bb.x, bb.y, bb.z, bb.w};
  short8 hv, lv;
#pragma unroll
  for (int k = 0; k < 8; k++) {
    int c = c0 + k;
    float val = (xs[k] - m[c]) * rsqrtf(v[c] + 1e-5f) * g[c] + b[c];
    if (relu) val = fmaxf(val, 0.f);
    __hip_bfloat16 h = __float2bfloat16(val);
    float hf = __bfloat162float(h);
    __hip_bfloat16 lo = __float2bfloat16(val - hf);
    hv[k] = (short)*reinterpret_cast<u16*>(&h);
    lv[k] = (short)*reinterpret_cast<u16*>(&lo);
  }
  *reinterpret_cast<short8*>(oh + i8) = hv;
  *reinterpret_cast<short8*>(ol + i8) = lv;
}

// ---------- bf16-split MFMA GEMM (double-buffered): C[M×N] f32 = [A1|A2] @ W ----------
// ep: 0 none, 1 +bias, 2 +bias+relu, 3 dual-write (C=raw, C2=dinv²·raw+bias),
//     4 bias+relu then bf16 hi/lo split to OH/OL. Stores guarded by cg<N.
__global__ __launch_bounds__(256) void k_mgemm(
    const u16* __restrict__ Ah1, const u16* __restrict__ Al1, int lda1,
    const u16* __restrict__ Ah2, const u16* __restrict__ Al2, int lda2, int Ksplit,
    const u16* __restrict__ Wth, const u16* __restrict__ Wtl,
    const float* __restrict__ bias, float* __restrict__ C, int N, int K, int ep,
    float* __restrict__ C2, const float* __restrict__ dinvp,
    u16* __restrict__ OH, u16* __restrict__ OL) {
  __shared__ u16 tA[2][2][4096];
  __shared__ u16 tB[2][2][4096];
  const int tid = threadIdx.x;
  const int w = tid >> 6, l = tid & 63;
  const int m0 = blockIdx.y * 64, n0 = blockIdx.x * 64;
  const int fr = l & 15, fq = l >> 4;

  f32x4 acc[2][2];
  const f32x4 fz = {0.f, 0.f, 0.f, 0.f};
#pragma unroll
  for (int i = 0; i < 2; i++)
#pragma unroll
    for (int j = 0; j < 2; j++) acc[i][j] = fz;

  auto stage = [&](int buf, int k0) {
#pragma unroll
    for (int q = 0; q < 2; q++) {
      int s = w * 2 + q;
      int kg = k0 + s * 8;
      const u16* ah; const u16* al; int ld; int kk = kg;
      if (kg < Ksplit) { ah = Ah1; al = Al1; ld = lda1; }
      else             { ah = Ah2; al = Al2; ld = lda2; kk = kg - Ksplit; }
      gld16(ah + (size_t)(m0 + l) * ld + kk, (char*)&tA[buf][0][0] + s * 1024);
      gld16(al + (size_t)(m0 + l) * ld + kk, (char*)&tA[buf][1][0] + s * 1024);
      gld16(Wth + (size_t)(n0 + l) * K + kg, (char*)&tB[buf][0][0] + s * 1024);
      gld16(Wtl + (size_t)(n0 + l) * K + kg, (char*)&tB[buf][1][0] + s * 1024);
    }
  };

  stage(0, 0);
  const int NT = K / GBK;
  int cur = 0;
  for (int kt = 0; kt < NT; kt++) {
    __syncthreads();
    if (kt + 1 < NT) stage(cur ^ 1, (kt + 1) * GBK);
#pragma unroll
    for (int kh = 0; kh < 2; kh++) {
      const int kb = (kh * 4 + fq) * 1024;
      short8 fa[2][2], fb[2][2];
#pragma unroll
      for (int i = 0; i < 2; i++) {
        int ar = (w >> 1) * 32 + i * 16 + fr;
        fa[0][i] = *reinterpret_cast<const short8*>((const char*)&tA[cur][0][0] + kb + ar * 16);
        fa[1][i] = *reinterpret_cast<const short8*>((const char*)&tA[cur][1][0] + kb + ar * 16);
        int br = (w & 1) * 32 + i * 16 + fr;
        fb[0][i] = *reinterpret_cast<const short8*>((const char*)&tB[cur][0][0] + kb + br * 16);
        fb[1][i] = *reinterpret_cast<const short8*>((const char*)&tB[cur][1][0] + kb + br * 16);
      }
#pragma unroll
      for (int i = 0; i < 2; i++)
#pragma unroll
        for (int j = 0; j < 2; j++) {
          acc[i][j] = __builtin_amdgcn_mfma_f32_16x16x32_bf16(fa[1][i], fb[0][j], acc[i][j], 0, 0, 0);
          acc[i][j] = __builtin_amdgcn_mfma_f32_16x16x32_bf16(fa[0][i], fb[1][j], acc[i][j], 0, 0, 0);
          acc[i][j] = __builtin_amdgcn_mfma_f32_16x16x32_bf16(fa[0][i], fb[0][j], acc[i][j], 0, 0, 0);
        }
    }
    cur ^= 1;
  }

#pragma unroll
  for (int i = 0; i < 2; i++) {
    int rg0 = m0 + (w >> 1) * 32 + i * 16 + fq * 4;
#pragma unroll
    for (int j = 0; j < 2; j++) {
      int cg = n0 + (w & 1) * 32 + j * 16 + fr;
      if (cg >= N) continue;
      float bv = (ep >= 1) ? bias[cg] : 0.f;
#pragma unroll
      for (int g = 0; g < 4; g++) {
        float raw = acc[i][j][g];
        size_t idx = (size_t)(rg0 + g) * N + cg;
        if (ep == 3) {
          float di = dinvp[rg0 + g];
          C[idx] = raw;
          C2[idx] = di * di * raw + bv;
        } else if (ep == 4) {
          float val = fmaxf(raw + bv, 0.f);
          __hip_bfloat16 h = __float2bfloat16(val);
          float hf = __bfloat162float(h);
          __hip_bfloat16 lo = __float2bfloat16(val - hf);
          OH[idx] = *reinterpret_cast<u16*>(&h);
          OL[idx] = *reinterpret_cast<u16*>(&lo);
        } else {
          float val = raw + bv;
          if (ep == 2) val = fmaxf(val, 0.f);
          C[idx] = val;
        }
      }
    }
  }
}

extern "C" void kernel_launch(void* const* d_in, const int* in_sizes, int n_in,
                              void* d_out, int out_size, void* d_ws, size_t ws_size,
                              hipStream_t stream) {
  const float* feat  = (const float*)d_in[0];
  const float* noise = (const float*)d_in[1];
  const float* bnf_g = (const float*)d_in[2];
  const float* bnf_b = (const float*)d_in[3];
  const float* bnf_m = (const float*)d_in[4];
  const float* bnf_v = (const float*)d_in[5];
  const float* W1 = (const float*)d_in[6];
  const float* b1 = (const float*)d_in[7];
  const float* W2 = (const float*)d_in[8];
  const float* b2 = (const float*)d_in[9];
  const float* W3 = (const float*)d_in[10];
  const float* b3 = (const float*)d_in[11];
  const float* bn1_g = (const float*)d_in[12];
  const float* bn1_b = (const float*)d_in[13];
  const float* bn1_m = (const float*)d_in[14];
  const float* bn1_v = (const float*)d_in[15];
  const float* bn2_g = (const float*)d_in[16];
  const float* bn2_b = (const float*)d_in[17];
  const float* bn2_m = (const float*)d_in[18];
  const float* bn2_v = (const float*)d_in[19];
  const float* bn3_g = (const float*)d_in[20];
  const float* bn3_b = (const float*)d_in[21];
  const float* bn3_m = (const float*)d_in[22];
  const float* bn3_v = (const float*)d_in[23];
  const float* Wc1 = (const float*)d_in[24];
  const float* bc1 = (const float*)d_in[25];
  const float* Wc2 = (const float*)d_in[26];
  const float* bc2 = (const float*)d_in[27];
  float* outp = (float*)d_out;

  char* w = (char*)d_ws;
  size_t off = 0;
  auto alloc = [&](size_t n) { void* p = w + off; off = (off + n + 255) & ~(size_t)255; return p; };
  u16*    Ahb  = (u16*)   alloc((size_t)Bn * Fn * 2);
  u16*    Alb  = (u16*)   alloc((size_t)Bn * Fn * 2);
  double* A64  = (double*)alloc(Fn * 8);
  double* C64  = (double*)alloc(Fn * 8);
  double* sq   = (double*)alloc(Bn * 8);
  u64*    part = (u64*)   alloc((size_t)Bn * 64 * 8 * 8);
  int*    cand = (int*)   alloc((size_t)Bn * NCAND * 4);
  int*    knn  = (int*)   alloc((size_t)Bn * Kn * 4);
  float*  deg  = (float*) alloc(Bn * 4);
  float*  dinv = (float*) alloc(Bn * 4);
  float*  g1   = (float*) alloc((size_t)Bn * Hn * 4);
  float*  g2   = (float*) alloc((size_t)Bn * Hn * 4);
  u16*    sh   = (u16*)   alloc((size_t)Bn * Hn * 2);
  u16*    sl   = (u16*)   alloc((size_t)Bn * Hn * 2);
  u16*    hidh = (u16*)   alloc((size_t)Bn * 128 * 2);
  u16*    hidl = (u16*)   alloc((size_t)Bn * 128 * 2);
  u16*    W1th = (u16*)   alloc((size_t)Fn * Hn * 2);
  u16*    W1tl = (u16*)   alloc((size_t)Fn * Hn * 2);
  u16*    W2th = (u16*)   alloc((size_t)Hn * Hn * 2);
  u16*    W2tl = (u16*)   alloc((size_t)Hn * Hn * 2);
  u16*    W3th = (u16*)   alloc((size_t)Hn * Hn * 2);
  u16*    W3tl = (u16*)   alloc((size_t)Hn * Hn * 2);
  u16*    Wc1th= (u16*)   alloc((size_t)(Hn + Fn) * 128 * 2);
  u16*    Wc1tl= (u16*)   alloc((size_t)(Hn + Fn) * 128 * 2);
  u16*    Wc2th= (u16*)   alloc((size_t)64 * 128 * 2);
  u16*    Wc2tl= (u16*)   alloc((size_t)64 * 128 * 2);
  (void)ws_size; (void)in_sizes; (void)n_in; (void)out_size;

  k_prep<<<(Fn + 255) / 256, 256, 0, stream>>>(bnf_g, bnf_b, bnf_m, bnf_v, A64, C64);
  k_bnsplit<<<Bn, Fn / 8, 0, stream>>>(feat, A64, C64, Ahb, Alb, sq, deg);
  k_wsplit_all<<<dim3(8, 56, 5), 256, 0, stream>>>(W1, W2, W3, Wc1, Wc2,
                                                   W1th, W1tl, W2th, W2tl, W3th, W3tl,
                                                   Wc1th, Wc1tl, Wc2th, Wc2tl);

  k_gram<<<2080, 256, 0, stream>>>(Ahb, sq, part);
  k_candmerge<<<Bn / 4, 256, 0, stream>>>(part, cand);
  k_rerank<<<Bn, 256, 0, stream>>>(feat, A64, C64, sq, noise, cand, knn, deg);
  k_dinv<<<(Bn + 255) / 256, 256, 0, stream>>>(deg, dinv);

  dim3 gm(Hn / 64, Bn / 64);
  // layer 1 (ep=3: g1 = h raw, g2 = di²h + b1)
  k_mgemm<<<gm, 256, 0, stream>>>(Ahb, Alb, Fn, Ahb, Alb, Fn, Fn, W1th, W1tl, b1, g1, Hn, Fn, 3,
                                  g2, dinv, nullptr, nullptr);
  k_aggsc<<<Bn, Hn, 0, stream>>>(g1, knn, dinv, g2);
  k_bnact_split<<<(Bn * Hn) / (256 * 8), 256, 0, stream>>>(g2, bn1_g, bn1_b, bn1_m, bn1_v, 1, sh, sl);
  // layer 2
  k_mgemm<<<gm, 256, 0, stream>>>(sh, sl, Hn, sh, sl, Hn, Hn, W2th, W2tl, b2, g1, Hn, Hn, 3,
                                  g2, dinv, nullptr, nullptr);
  k_aggsc<<<Bn, Hn, 0, stream>>>(g1, knn, dinv, g2);
  k_bnact_split<<<(Bn * Hn) / (256 * 8), 256, 0, stream>>>(g2, bn2_g, bn2_b, bn2_m, bn2_v, 1, sh, sl);
  // layer 3
  k_mgemm<<<gm, 256, 0, stream>>>(sh, sl, Hn, sh, sl, Hn, Hn, W3th, W3tl, b3, g1, Hn, Hn, 3,
                                  g2, dinv, nullptr, nullptr);
  k_aggsc<<<Bn, Hn, 0, stream>>>(g1, knn, dinv, g2);
  k_bnact_split<<<(Bn * Hn) / (256 * 8), 256, 0, stream>>>(g2, bn3_g, bn3_b, bn3_m, bn3_v, 0, sh, sl);
  // classifier1: comb = [h3 | x], ep=4 -> bf16-split hid
  k_mgemm<<<dim3(128 / 64, Bn / 64), 256, 0, stream>>>(sh, sl, Hn, Ahb, Alb, Fn, Hn,
                                                       Wc1th, Wc1tl, bc1, nullptr, 128, Hn + Fn, 4,
                                                       nullptr, nullptr, hidh, hidl);
  // classifier2: MFMA, N=38 guarded
  k_mgemm<<<dim3(1, Bn / 64), 256, 0, stream>>>(hidh, hidl, 128, hidh, hidl, 128, 128,
                                                Wc2th, Wc2tl, bc2, outp, Cn, 128, 1,
                                                nullptr, nullptr, nullptr, nullptr);
}